// Round 3
// baseline (233.554 us; speedup 1.0000x reference)
//
#include <hip/hip_runtime.h>
#include <hip/hip_bf16.h>

typedef __bf16 bf16x8 __attribute__((ext_vector_type(8)));
typedef short s16x4 __attribute__((ext_vector_type(4)));
typedef float floatx4 __attribute__((ext_vector_type(4)));
typedef __hip_bfloat16 bf16;

#define T_SEQ 2048
#define NH 16
#define HD 64
#define CDIM 1024

// async global->LDS, 16B/lane. ldsbase MUST be wave-uniform; HW stores lane i at ldsbase+i*16.
__device__ __forceinline__ void gload16(const bf16* g, bf16* ldsbase) {
  __builtin_amdgcn_global_load_lds((const __attribute__((address_space(1))) void*)g,
                                   (__attribute__((address_space(3))) void*)ldsbase, 16, 0, 0);
}

// ---------------- fused prep: cast x, transpose+cast Wqkv & Wo, rope table ----------------
__global__ __launch_bounds__(256) void prep_kernel(const float* __restrict__ x,
                                                   const float* __restrict__ Wqkv,
                                                   const float* __restrict__ Wo,
                                                   bf16* __restrict__ Xb,
                                                   bf16* __restrict__ WqkvT,
                                                   bf16* __restrict__ WoT,
                                                   float2* __restrict__ tab) {
  __shared__ float tile[32][33];
  const int bid = blockIdx.x, tid = threadIdx.x;
  if (bid < 4096) {
    int i = bid * 256 + tid;
    const float4 v = ((const float4*)x)[i];
    union { bf16 h[4]; uint2 u; } pk;
    pk.h[0] = __float2bfloat16(v.x);
    pk.h[1] = __float2bfloat16(v.y);
    pk.h[2] = __float2bfloat16(v.z);
    pk.h[3] = __float2bfloat16(v.w);
    ((uint2*)Xb)[i] = pk.u;
  } else if (bid < 8192) {
    const float* in;
    bf16* out;
    int bx, by, R, Cc;
    if (bid < 7168) {
      int t = bid - 4096;
      in = Wqkv; out = WqkvT; R = 1024; Cc = 3072;
      bx = (t % 96) * 32; by = (t / 96) * 32;
    } else {
      int t = bid - 7168;
      in = Wo; out = WoT; R = 1024; Cc = 1024;
      bx = (t & 31) * 32; by = (t >> 5) * 32;
    }
    const int tx = tid & 31, ty = tid >> 5;
#pragma unroll
    for (int i = 0; i < 32; i += 8)
      tile[ty + i][tx] = in[(size_t)(by + ty + i) * Cc + bx + tx];
    __syncthreads();
#pragma unroll
    for (int i = 0; i < 32; i += 8)
      out[(size_t)(bx + ty + i) * R + by + tx] = __float2bfloat16(tile[tx][ty + i]);
  } else {
    int idx = (bid - 8192) * 256 + tid;  // 2048*32
    int t = idx >> 5, j = idx & 31;
    float w = exp2f(-13.287712379549449f * (float)(2 * j + 1) * (1.0f / 64.0f));
    float ang = (float)(t + 1) * w;
    tab[idx] = make_float2(cosf(ang), sinf(ang));
  }
}

// ---------------- 128x128x(BK=64) bf16 MFMA GEMM, B^T input, 2-PHASE DOUBLE-BUFFER ------
// T3 minimum 2-phase (learn_hip m230/m248): stage(t+1) issued BEFORE compute(t); the
// vmcnt(0) drain implicit in __syncthreads lands AFTER ~300cy of MFMA instead of before.
// One barrier per K-step. K%128==0 -> 2x unrolled loop gives static buffer addressing.
// MODE 1 epilogue pre-scales Q by 0.125 and repacks via LDS for coalesced 16B stores.
// Q stored TRANSPOSED [bh][d][t] (like Vt); K stays [bh][t][d].
template <int MODE>
__global__ __launch_bounds__(256) void gemm_bt(
    const bf16* __restrict__ A, const bf16* __restrict__ BT, float* __restrict__ CoutF,
    const float2* __restrict__ tab, bf16* __restrict__ Qt, bf16* __restrict__ Kr,
    bf16* __restrict__ Vt, int M, int N, int K) {
  constexpr int LDK = 64;
  constexpr int PADC = 136;  // bf16 elems; 272B row stride = 17*16B
  __shared__ __align__(16) bf16 smem[32768];  // 64 KiB: dbuf{As,Bs}x2; epilogue reuses
  bf16* const As0 = smem;            // 8192 elems (16 KiB) each
  bf16* const Bs0 = smem + 8192;
  bf16* const As1 = smem + 16384;
  bf16* const Bs1 = smem + 24576;
  const int tid = threadIdx.x, lane = tid & 63, wave = tid >> 6;
  const int quad = lane >> 4, c16 = lane & 15;
  const int tile_m = blockIdx.y * 128, tile_n = blockIdx.x * 128;
  const int wm = (wave >> 1) * 64, wn = (wave & 1) * 64;
  const int r0 = tid >> 3;                       // staging row 0..31 (+32i)
  const int csw = ((tid & 7) ^ (r0 & 7)) * 8;    // swizzled global chunk offset (elems)
  const int s1 = (quad ^ (c16 & 7)) * 8;         // read slot, k-half 0
  const int s2 = s1 ^ 32;                        // read slot, k-half 1
  floatx4 acc[4][4] = {};

  auto stage = [&](bf16* __restrict__ Asb, bf16* __restrict__ Bsb, int k0) {
#pragma unroll
    for (int i = 0; i < 4; i++) {
      gload16(&A[(size_t)(tile_m + r0 + i * 32) * K + k0 + csw], &Asb[i * 2048 + wave * 512]);
      gload16(&BT[(size_t)(tile_n + r0 + i * 32) * K + k0 + csw], &Bsb[i * 2048 + wave * 512]);
    }
  };
  auto compute = [&](const bf16* __restrict__ Asb, const bf16* __restrict__ Bsb) {
    bf16x8 af[4], bfr[4];
#pragma unroll
    for (int i = 0; i < 4; i++) {
      af[i] = *(const bf16x8*)&Asb[(wm + i * 16 + c16) * LDK + s1];
      bfr[i] = *(const bf16x8*)&Bsb[(wn + i * 16 + c16) * LDK + s1];
    }
#pragma unroll
    for (int mi = 0; mi < 4; mi++)
#pragma unroll
      for (int ni = 0; ni < 4; ni++)
        acc[mi][ni] = __builtin_amdgcn_mfma_f32_16x16x32_bf16(af[mi], bfr[ni], acc[mi][ni], 0, 0, 0);
#pragma unroll
    for (int i = 0; i < 4; i++) {
      af[i] = *(const bf16x8*)&Asb[(wm + i * 16 + c16) * LDK + s2];
      bfr[i] = *(const bf16x8*)&Bsb[(wn + i * 16 + c16) * LDK + s2];
    }
#pragma unroll
    for (int mi = 0; mi < 4; mi++)
#pragma unroll
      for (int ni = 0; ni < 4; ni++)
        acc[mi][ni] = __builtin_amdgcn_mfma_f32_16x16x32_bf16(af[mi], bfr[ni], acc[mi][ni], 0, 0, 0);
  };

  // prologue
  stage(As0, Bs0, 0);
  __syncthreads();  // drain prologue loads (vmcnt(0)) + all waves ready
  // main: 2x unrolled so buffer selection is compile-time static
  for (int k0 = 0; k0 < K; k0 += 128) {
    if (k0 + 64 < K) stage(As1, Bs1, k0 + 64);   // issue next-tile loads FIRST
    compute(As0, Bs0);                            // MFMA hides the load latency
    __syncthreads();                              // drain + buffer handoff
    if (k0 + 128 < K) stage(As0, Bs0, k0 + 128);
    compute(As1, Bs1);
    __syncthreads();
  }
  // ---- epilogue: smem is free now (last barrier above) ----
  // C/D layout (m89): col = lane&15, row = quad*4 + reg
  if (MODE == 0) {
    // fp32 output, two 64-row passes through LDS ([64][132] fp32 = 33792 B)
    float* Ctf = (float*)smem;
#pragma unroll
    for (int p = 0; p < 2; p++) {
      if ((wave >> 1) == p) {
#pragma unroll
        for (int mi = 0; mi < 4; mi++) {
          int rl = mi * 16 + quad * 4;  // local row within this 64-row half
#pragma unroll
          for (int ni = 0; ni < 4; ni++) {
            int col = wn + ni * 16 + c16;
#pragma unroll
            for (int r = 0; r < 4; r++)
              Ctf[(rl + r) * 132 + col] = acc[mi][ni][r];
          }
        }
      }
      __syncthreads();
#pragma unroll
      for (int i = 0; i < 8; i++) {
        int e = tid + i * 256;          // 64 rows x 32 col-chunks
        int row = e >> 5, cb = (e & 31) * 4;
        floatx4 v4 = *(const floatx4*)&Ctf[row * 132 + cb];
        *(floatx4*)&CoutF[(size_t)(tile_m + p * 64 + row) * N + tile_n + cb] = v4;
      }
      __syncthreads();  // readers done before next pass overwrites
    }
  } else {
    const int seg = tile_n >> 10;  // block-uniform: 0=Q 1=K 2=V (tile never straddles segs)
    const int bq = tile_m >> 11;   // batch index (tiles never straddle batch: 128 | 2048)
    const int tg0 = tile_m & 2047; // t offset within batch
    bf16* Ct = smem;               // [128][PADC] = 34816 B, fits in 64 KiB
    if (seg != 1) {
      // Q and V go to [bh][d][t]: store Ct COLUMN-major [col][row] (row = t, contiguous)
#pragma unroll
      for (int ni = 0; ni < 4; ni++) {
        const int col = wn + ni * 16 + c16;
        const int cc = (tile_n + col) & 1023;
        const int j = (cc & 63) >> 1;
#pragma unroll
        for (int mi = 0; mi < 4; mi++) {
          const int row0 = wm + mi * 16 + quad * 4;
          union { bf16 h[4]; s16x4 sv; } ph;
#pragma unroll
          for (int r = 0; r < 4; r++) {
            float val = acc[mi][ni][r];
            float outv;
            if (seg == 0) {  // RoPE + fold 1/sqrt(D); partner lane holds col^1 (= d^1)
              float partner = __shfl_xor(val, 1, 64);
              float2 sc = tab[(tg0 + row0 + r) * 32 + j];
              outv = (((cc & 1) == 0) ? (val * sc.x - partner * sc.y)
                                      : (val * sc.x + partner * sc.y)) * 0.125f;
            } else {
              outv = val;
            }
            ph.h[r] = __float2bfloat16(outv);
          }
          *(s16x4*)&Ct[col * PADC + row0] = ph.sv;  // 8B write, 4 consecutive t
        }
      }
      __syncthreads();
      bf16* dst = (seg == 0) ? Qt : Vt;
#pragma unroll
      for (int i = 0; i < 8; i++) {
        int e = tid + i * 256;  // 128 cols x 16 t-chunks
        int col = e >> 4, tb = (e & 15) * 8;
        bf16x8 vv = *(const bf16x8*)&Ct[col * PADC + tb];
        int h = ((tile_n & 1023) + col) >> 6, d = col & 63;
        *(bf16x8*)&dst[((size_t)(bq * NH + h) * HD + d) * T_SEQ + tg0 + tb] = vv;
      }
    } else {
      // K stays [bh][t][d]: store Ct ROW-major [row][col] (col = d, contiguous)
#pragma unroll
      for (int ni = 0; ni < 4; ni++) {
        const int col = wn + ni * 16 + c16;
        const int cc = (tile_n + col) & 1023;
        const int j = (cc & 63) >> 1;
#pragma unroll
        for (int mi = 0; mi < 4; mi++) {
          const int row0 = wm + mi * 16 + quad * 4;
#pragma unroll
          for (int r = 0; r < 4; r++) {
            float val = acc[mi][ni][r];
            float partner = __shfl_xor(val, 1, 64);
            float2 sc = tab[(tg0 + row0 + r) * 32 + j];
            float outv = ((cc & 1) == 0) ? (val * sc.x - partner * sc.y)
                                         : (val * sc.x + partner * sc.y);
            Ct[(row0 + r) * PADC + col] = __float2bfloat16(outv);
          }
        }
      }
      __syncthreads();
#pragma unroll
      for (int i = 0; i < 8; i++) {
        int e = tid + i * 256;  // 128 rows x 16 d-chunks
        int row = e >> 4, db = (e & 15) * 8;
        bf16x8 vv = *(const bf16x8*)&Ct[row * PADC + db];
        int h = ((tile_n & 1023) + db) >> 6, d = db & 63;
        *(bf16x8*)&Kr[((size_t)(bq * NH + h) * T_SEQ + tg0 + row) * HD + d] = vv;
      }
    }
  }
}

// ---------------- flash attention v3: barrier-free, direct-L2 K/V fragments ----------------
// 512 blocks = 16 qtiles(128 q) x 32 bh; 4 waves x 32 q (2 q-fragments per wave).
// K fragment  = contiguous 16B of Kr[bh][t][d]      (A-operand, row=c16=t, k=quad*8+j=d)
// V fragment  = contiguous 16B of Vt[bh][d][t]      (B-operand, col=c16=d, k=quad*8+j=t)
// Q fragment  = gathered once per block from Qt[bh][d][t]
// Both K/V are L2-resident (512 KB/bh); no LDS staging, NO __syncthreads in the kernel.
// LDS only holds the wave-private P tile (S^T -> A-operand transpose), ordered by lgkmcnt.
// Fixed-shift softmax in exp2 domain: P = exp2(s*log2e - 5*log2e), l deferred per-lane.
__global__ __launch_bounds__(256, 4) void attn_kernel(const bf16* __restrict__ Qt,
                                                      const bf16* __restrict__ Kr,
                                                      const bf16* __restrict__ Vt,
                                                      bf16* __restrict__ Y) {
  constexpr int PPAD = 72;                 // P row stride (bf16); 144B = 9*16B (b128-aligned)
  constexpr float LOG2E = 1.44269504f;
  constexpr float FM2 = 7.21347520f;       // 5.0*log2(e): fixed softmax shift (exp2 domain)
  __shared__ __align__(16) bf16 Ps[4][32 * PPAD];  // wave-private P [q_local][k], 18 KiB
  const int idx = blockIdx.x;
  const int bh = idx & 31;
  const int q8 = (idx >> 5) & 7;
  const int qtile = (idx < 256) ? (15 - q8) : q8;  // pair qtile q with 15-q per CU: work sums const
  const int b = bh >> 4, h = bh & 15;
  const int tid = threadIdx.x, lane = tid & 63, wave = tid >> 6;
  const int quad = lane >> 4, c16 = lane & 15;
  const size_t hoff = (size_t)bh * T_SEQ * HD;
  const int q0 = qtile * 128 + wave * 32;
  bf16* const Psw = Ps[wave];
  // Q fragments: qf[f][dh][j] = Q[d=dh*32+quad*8+j][t=q0+f*16+c16]  (32 scalar loads, once)
  bf16x8 qf[2][2];
#pragma unroll
  for (int f = 0; f < 2; f++)
#pragma unroll
    for (int dh = 0; dh < 2; dh++)
#pragma unroll
      for (int j = 0; j < 8; j++)
        qf[f][dh][j] =
            *(const __bf16*)&Qt[hoff + (size_t)(dh * 32 + quad * 8 + j) * T_SEQ + q0 + f * 16 + c16];
  floatx4 o_acc[2][4] = {};  // o_acc[f][dt][r]: q=q0+f*16+quad*4+r, d=dt*16+c16
  float l_run[2] = {0.f, 0.f};

  auto do_half = [&](int kbase, bool domask) {
    // ---- QK^T (S^T): z[f][nt][r] holds k=kbase+nt*16+quad*4+r, q=q0+f*16+c16 ----
    floatx4 z[2][4];
#pragma unroll
    for (int nt = 0; nt < 4; nt++) {
      const bf16* kp = &Kr[hoff + (size_t)(kbase + nt * 16 + c16) * HD + quad * 8];
      bf16x8 kf0 = *(const bf16x8*)kp;
      bf16x8 kf1 = *(const bf16x8*)(kp + 32);
#pragma unroll
      for (int f = 0; f < 2; f++) {
        floatx4 zz = {0.f, 0.f, 0.f, 0.f};
        zz = __builtin_amdgcn_mfma_f32_16x16x32_bf16(kf0, qf[f][0], zz, 0, 0, 0);
        zz = __builtin_amdgcn_mfma_f32_16x16x32_bf16(kf1, qf[f][1], zz, 0, 0, 0);
        z[f][nt] = zz;
      }
    }
    // ---- P = exp2(s*log2e - FM2), mask tail, accumulate l, store to wave-private LDS ----
#pragma unroll
    for (int f = 0; f < 2; f++) {
      const int qg = q0 + f * 16 + c16;
#pragma unroll
      for (int nt = 0; nt < 4; nt++) {
        union { bf16 h4[4]; s16x4 sv; } ph;
#pragma unroll
        for (int r = 0; r < 4; r++) {
          float pp = __builtin_amdgcn_exp2f(fmaf(z[f][nt][r], LOG2E, -FM2));
          if (domask) {
            int kg = kbase + nt * 16 + quad * 4 + r;
            pp = (kg <= qg) ? pp : 0.f;
          }
          l_run[f] += pp;
          ph.h4[r] = __float2bfloat16(pp);
        }
        *(s16x4*)&Psw[(f * 16 + c16) * PPAD + nt * 16 + quad * 4] = ph.sv;
      }
    }
    // ---- PV: pf from LDS (A-operand transpose), vf direct from global (L2-hot) ----
    bf16x8 pf[2][2];
#pragma unroll
    for (int f = 0; f < 2; f++)
#pragma unroll
      for (int ks = 0; ks < 2; ks++)
        pf[f][ks] = *(const bf16x8*)&Psw[(f * 16 + c16) * PPAD + ks * 32 + quad * 8];
#pragma unroll
    for (int dt = 0; dt < 4; dt++) {
      const bf16* vp = &Vt[hoff + (size_t)(dt * 16 + c16) * T_SEQ + kbase + quad * 8];
      bf16x8 vf0 = *(const bf16x8*)vp;
      bf16x8 vf1 = *(const bf16x8*)(vp + 32);
#pragma unroll
      for (int f = 0; f < 2; f++) {
        o_acc[f][dt] = __builtin_amdgcn_mfma_f32_16x16x32_bf16(pf[f][0], vf0, o_acc[f][dt], 0, 0, 0);
        o_acc[f][dt] = __builtin_amdgcn_mfma_f32_16x16x32_bf16(pf[f][1], vf1, o_acc[f][dt], 0, 0, 0);
      }
    }
  };

  // full supertiles (no masking: all keys < q0 for every wave)
  for (int st = 0; st < qtile; ++st) {
    do_half(st * 128, false);
    do_half(st * 128 + 64, false);
  }
  // diagonal supertile: waves 0,1 need only keys [0,64) (h=1 fully masked -> skipped);
  // waves 2,3: h=0 needs no mask (keys<64 <= q>=64), h=1 masked.
  do_half(qtile * 128, wave < 2);
  if (wave >= 2) do_half(qtile * 128 + 64, true);

  // ---- epilogue: reduce l across quads (q=c16), broadcast 1/l to rows, store O[q][d] ----
#pragma unroll
  for (int f = 0; f < 2; f++) {
    float l = l_run[f];
    l += __shfl_xor(l, 16, 64);
    l += __shfl_xor(l, 32, 64);
    float linv = 1.0f / l;
    float l_bc[4];
#pragma unroll
    for (int r = 0; r < 4; r++) l_bc[r] = __shfl(linv, quad * 4 + r, 16);
#pragma unroll
    for (int dt = 0; dt < 4; dt++)
#pragma unroll
      for (int r = 0; r < 4; r++) {
        int t = q0 + f * 16 + quad * 4 + r;
        Y[((size_t)(b * T_SEQ + t)) * CDIM + h * HD + dt * 16 + c16] =
            __float2bfloat16(o_acc[f][dt][r] * l_bc[r]);
      }
  }
}

// ---------------- launch ----------------
extern "C" void kernel_launch(void* const* d_in, const int* in_sizes, int n_in,
                              void* d_out, int out_size, void* d_ws, size_t ws_size,
                              hipStream_t stream) {
  const float* x    = (const float*)d_in[0];   // [B,T,C] fp32
  const float* Wqkv = (const float*)d_in[2];   // [C,3C] fp32
  const float* Wo   = (const float*)d_in[3];   // [C,C] fp32
  float* out = (float*)d_out;                  // [B,T,C] fp32

  bf16* ws    = (bf16*)d_ws;
  bf16* Xb    = ws;                          // [4096][1024]
  bf16* WqkvT = Xb + 4194304;                // [3072][1024]
  bf16* WoT   = WqkvT + 3072 * 1024;         // [1024][1024]
  bf16* Qt    = WoT + 1024 * 1024;           // [B,H,D,T] (pre-scaled by 0.125, transposed)
  bf16* Kr    = Qt + 4194304;                // [B,H,T,D]
  bf16* Vt    = Kr + 4194304;                // [B,H,D,T]
  bf16* Y     = Vt + 4194304;                // [B,T,C]
  float2* tab = (float2*)(Y + 4194304);      // [T][32]

  prep_kernel<<<dim3(8448), 256, 0, stream>>>(x, Wqkv, Wo, Xb, WqkvT, WoT, tab);
  gemm_bt<1><<<dim3(3072 / 128, 4096 / 128), 256, 0, stream>>>(
      Xb, WqkvT, nullptr, tab, Qt, Kr, Vt, 4096, 3072, 1024);
  attn_kernel<<<dim3(512), 256, 0, stream>>>(Qt, Kr, Vt, Y);
  gemm_bt<0><<<dim3(1024 / 128, 4096 / 128), 256, 0, stream>>>(
      Y, WoT, out, nullptr, nullptr, nullptr, nullptr, 4096, 1024, 1024);
}

// Round 5
// 182.090 us; speedup vs baseline: 1.2826x; 1.2826x over previous
//
#include <hip/hip_runtime.h>
#include <hip/hip_bf16.h>

typedef __bf16 bf16x8 __attribute__((ext_vector_type(8)));
typedef short s16x4 __attribute__((ext_vector_type(4)));
typedef float floatx4 __attribute__((ext_vector_type(4)));
typedef __hip_bfloat16 bf16;

#define T_SEQ 2048
#define NH 16
#define HD 64
#define CDIM 1024

// async global->LDS, 16B/lane. ldsbase MUST be wave-uniform; HW stores lane i at ldsbase+i*16.
__device__ __forceinline__ void gload16(const bf16* g, bf16* ldsbase) {
  __builtin_amdgcn_global_load_lds((const __attribute__((address_space(1))) void*)g,
                                   (__attribute__((address_space(3))) void*)ldsbase, 16, 0, 0);
}

// ---------------- fused prep: cast x, transpose+cast Wqkv & Wo, rope table ----------------
__global__ __launch_bounds__(256) void prep_kernel(const float* __restrict__ x,
                                                   const float* __restrict__ Wqkv,
                                                   const float* __restrict__ Wo,
                                                   bf16* __restrict__ Xb,
                                                   bf16* __restrict__ WqkvT,
                                                   bf16* __restrict__ WoT,
                                                   float2* __restrict__ tab) {
  __shared__ float tile[32][33];
  const int bid = blockIdx.x, tid = threadIdx.x;
  if (bid < 4096) {
    int i = bid * 256 + tid;
    const float4 v = ((const float4*)x)[i];
    union { bf16 h[4]; uint2 u; } pk;
    pk.h[0] = __float2bfloat16(v.x);
    pk.h[1] = __float2bfloat16(v.y);
    pk.h[2] = __float2bfloat16(v.z);
    pk.h[3] = __float2bfloat16(v.w);
    ((uint2*)Xb)[i] = pk.u;
  } else if (bid < 8192) {
    const float* in;
    bf16* out;
    int bx, by, R, Cc;
    if (bid < 7168) {
      int t = bid - 4096;
      in = Wqkv; out = WqkvT; R = 1024; Cc = 3072;
      bx = (t % 96) * 32; by = (t / 96) * 32;
    } else {
      int t = bid - 7168;
      in = Wo; out = WoT; R = 1024; Cc = 1024;
      bx = (t & 31) * 32; by = (t >> 5) * 32;
    }
    const int tx = tid & 31, ty = tid >> 5;
#pragma unroll
    for (int i = 0; i < 32; i += 8)
      tile[ty + i][tx] = in[(size_t)(by + ty + i) * Cc + bx + tx];
    __syncthreads();
#pragma unroll
    for (int i = 0; i < 32; i += 8)
      out[(size_t)(bx + ty + i) * R + by + tx] = __float2bfloat16(tile[tx][ty + i]);
  } else {
    int idx = (bid - 8192) * 256 + tid;  // 2048*32
    int t = idx >> 5, j = idx & 31;
    float w = exp2f(-13.287712379549449f * (float)(2 * j + 1) * (1.0f / 64.0f));
    float ang = (float)(t + 1) * w;
    tab[idx] = make_float2(cosf(ang), sinf(ang));
  }
}

// ---------------- 128x128x(BK=64) bf16 MFMA GEMM, B^T input, 2-PHASE DOUBLE-BUFFER ------
template <int MODE>
__global__ __launch_bounds__(256) void gemm_bt(
    const bf16* __restrict__ A, const bf16* __restrict__ BT, float* __restrict__ CoutF,
    const float2* __restrict__ tab, bf16* __restrict__ Qt, bf16* __restrict__ Kr,
    bf16* __restrict__ Vt, int M, int N, int K) {
  constexpr int LDK = 64;
  constexpr int PADC = 136;  // bf16 elems; 272B row stride = 17*16B
  __shared__ __align__(16) bf16 smem[32768];  // 64 KiB: dbuf{As,Bs}x2; epilogue reuses
  bf16* const As0 = smem;            // 8192 elems (16 KiB) each
  bf16* const Bs0 = smem + 8192;
  bf16* const As1 = smem + 16384;
  bf16* const Bs1 = smem + 24576;
  const int tid = threadIdx.x, lane = tid & 63, wave = tid >> 6;
  const int quad = lane >> 4, c16 = lane & 15;
  const int tile_m = blockIdx.y * 128, tile_n = blockIdx.x * 128;
  const int wm = (wave >> 1) * 64, wn = (wave & 1) * 64;
  const int r0 = tid >> 3;                       // staging row 0..31 (+32i)
  const int csw = ((tid & 7) ^ (r0 & 7)) * 8;    // swizzled global chunk offset (elems)
  const int s1 = (quad ^ (c16 & 7)) * 8;         // read slot, k-half 0
  const int s2 = s1 ^ 32;                        // read slot, k-half 1
  floatx4 acc[4][4] = {};

  auto stage = [&](bf16* __restrict__ Asb, bf16* __restrict__ Bsb, int k0) {
#pragma unroll
    for (int i = 0; i < 4; i++) {
      gload16(&A[(size_t)(tile_m + r0 + i * 32) * K + k0 + csw], &Asb[i * 2048 + wave * 512]);
      gload16(&BT[(size_t)(tile_n + r0 + i * 32) * K + k0 + csw], &Bsb[i * 2048 + wave * 512]);
    }
  };
  auto compute = [&](const bf16* __restrict__ Asb, const bf16* __restrict__ Bsb) {
    bf16x8 af[4], bfr[4];
#pragma unroll
    for (int i = 0; i < 4; i++) {
      af[i] = *(const bf16x8*)&Asb[(wm + i * 16 + c16) * LDK + s1];
      bfr[i] = *(const bf16x8*)&Bsb[(wn + i * 16 + c16) * LDK + s1];
    }
#pragma unroll
    for (int mi = 0; mi < 4; mi++)
#pragma unroll
      for (int ni = 0; ni < 4; ni++)
        acc[mi][ni] = __builtin_amdgcn_mfma_f32_16x16x32_bf16(af[mi], bfr[ni], acc[mi][ni], 0, 0, 0);
#pragma unroll
    for (int i = 0; i < 4; i++) {
      af[i] = *(const bf16x8*)&Asb[(wm + i * 16 + c16) * LDK + s2];
      bfr[i] = *(const bf16x8*)&Bsb[(wn + i * 16 + c16) * LDK + s2];
    }
#pragma unroll
    for (int mi = 0; mi < 4; mi++)
#pragma unroll
      for (int ni = 0; ni < 4; ni++)
        acc[mi][ni] = __builtin_amdgcn_mfma_f32_16x16x32_bf16(af[mi], bfr[ni], acc[mi][ni], 0, 0, 0);
  };

  // prologue
  stage(As0, Bs0, 0);
  __syncthreads();  // drain prologue loads (vmcnt(0)) + all waves ready
  // main: 2x unrolled so buffer selection is compile-time static
  for (int k0 = 0; k0 < K; k0 += 128) {
    if (k0 + 64 < K) stage(As1, Bs1, k0 + 64);   // issue next-tile loads FIRST
    compute(As0, Bs0);                            // MFMA hides the load latency
    __syncthreads();                              // drain + buffer handoff
    if (k0 + 128 < K) stage(As0, Bs0, k0 + 128);
    compute(As1, Bs1);
    __syncthreads();
  }
  // ---- epilogue: smem is free now (last barrier above) ----
  // C/D layout (m89): col = lane&15, row = quad*4 + reg
  if (MODE == 0) {
    // fp32 output, two 64-row passes through LDS ([64][132] fp32 = 33792 B)
    float* Ctf = (float*)smem;
#pragma unroll
    for (int p = 0; p < 2; p++) {
      if ((wave >> 1) == p) {
#pragma unroll
        for (int mi = 0; mi < 4; mi++) {
          int rl = mi * 16 + quad * 4;  // local row within this 64-row half
#pragma unroll
          for (int ni = 0; ni < 4; ni++) {
            int col = wn + ni * 16 + c16;
#pragma unroll
            for (int r = 0; r < 4; r++)
              Ctf[(rl + r) * 132 + col] = acc[mi][ni][r];
          }
        }
      }
      __syncthreads();
#pragma unroll
      for (int i = 0; i < 8; i++) {
        int e = tid + i * 256;          // 64 rows x 32 col-chunks
        int row = e >> 5, cb = (e & 31) * 4;
        floatx4 v4 = *(const floatx4*)&Ctf[row * 132 + cb];
        *(floatx4*)&CoutF[(size_t)(tile_m + p * 64 + row) * N + tile_n + cb] = v4;
      }
      __syncthreads();  // readers done before next pass overwrites
    }
  } else {
    const int seg = tile_n >> 10;  // block-uniform: 0=Q 1=K 2=V (tile never straddles segs)
    const int bq = tile_m >> 11;   // batch index (tiles never straddle batch: 128 | 2048)
    const int tg0 = tile_m & 2047; // t offset within batch
    bf16* Ct = smem;               // [128][PADC] = 34816 B, fits in 64 KiB
    if (seg != 1) {
      // Q and V go to [bh][d][t]: store Ct COLUMN-major [col][row] (row = t, contiguous)
#pragma unroll
      for (int ni = 0; ni < 4; ni++) {
        const int col = wn + ni * 16 + c16;
        const int cc = (tile_n + col) & 1023;
        const int j = (cc & 63) >> 1;
#pragma unroll
        for (int mi = 0; mi < 4; mi++) {
          const int row0 = wm + mi * 16 + quad * 4;
          union { bf16 h[4]; s16x4 sv; } ph;
#pragma unroll
          for (int r = 0; r < 4; r++) {
            float val = acc[mi][ni][r];
            float outv;
            if (seg == 0) {  // RoPE + fold 1/sqrt(D); partner lane holds col^1 (= d^1)
              float partner = __shfl_xor(val, 1, 64);
              float2 sc = tab[(tg0 + row0 + r) * 32 + j];
              outv = (((cc & 1) == 0) ? (val * sc.x - partner * sc.y)
                                      : (val * sc.x + partner * sc.y)) * 0.125f;
            } else {
              outv = val;
            }
            ph.h[r] = __float2bfloat16(outv);
          }
          *(s16x4*)&Ct[col * PADC + row0] = ph.sv;  // 8B write, 4 consecutive t
        }
      }
      __syncthreads();
      bf16* dst = (seg == 0) ? Qt : Vt;
#pragma unroll
      for (int i = 0; i < 8; i++) {
        int e = tid + i * 256;  // 128 cols x 16 t-chunks
        int col = e >> 4, tb = (e & 15) * 8;
        bf16x8 vv = *(const bf16x8*)&Ct[col * PADC + tb];
        int h = ((tile_n & 1023) + col) >> 6, d = col & 63;
        *(bf16x8*)&dst[((size_t)(bq * NH + h) * HD + d) * T_SEQ + tg0 + tb] = vv;
      }
    } else {
      // K stays [bh][t][d]: store Ct ROW-major [row][col] (col = d, contiguous)
#pragma unroll
      for (int ni = 0; ni < 4; ni++) {
        const int col = wn + ni * 16 + c16;
        const int cc = (tile_n + col) & 1023;
        const int j = (cc & 63) >> 1;
#pragma unroll
        for (int mi = 0; mi < 4; mi++) {
          const int row0 = wm + mi * 16 + quad * 4;
#pragma unroll
          for (int r = 0; r < 4; r++) {
            float val = acc[mi][ni][r];
            float partner = __shfl_xor(val, 1, 64);
            float2 sc = tab[(tg0 + row0 + r) * 32 + j];
            float outv = ((cc & 1) == 0) ? (val * sc.x - partner * sc.y)
                                         : (val * sc.x + partner * sc.y);
            Ct[(row0 + r) * PADC + col] = __float2bfloat16(outv);
          }
        }
      }
      __syncthreads();
#pragma unroll
      for (int i = 0; i < 8; i++) {
        int e = tid + i * 256;  // 128 rows x 16 d-chunks
        int row = e >> 4, db = (e & 15) * 8;
        bf16x8 vv = *(const bf16x8*)&Ct[row * PADC + db];
        int h = ((tile_n & 1023) + db) >> 6, d = db & 63;
        *(bf16x8*)&Kr[((size_t)(bq * NH + h) * T_SEQ + tg0 + row) * HD + d] = vv;
      }
    }
  }
}

// ---------------- flash attention v4b: 128q blocks, LDS-staged K/V via gload_lds ---------
// 512 blocks = 16 qtiles(128 q) x 32 bh; 4 waves x 32 q (2 q-fragments/wave) -> K/V LDS
// fragment reads amortized over 2x MFMAs vs the 64q version; total 64-key tiles halve.
// K/V staged with the gemm's proven swizzle: linear LDS dest (gload_lds) + XOR-swizzled
// per-lane GLOBAL source; reads use s1=(quad^(c16&7))*8 (bank-conflict-free, measured 0).
// 2-phase double-buffer: stage(next) issued before compute(cur); one barrier per tile.
// P tile: PPAD=72 elems/row (row MUST hold 64 k-values; 144B = 9*16B keeps b128 aligned).
// v4's PPAD=40 overlapped P rows -> correctness bug; fixed here.
__global__ __launch_bounds__(256) void attn_kernel(const bf16* __restrict__ Qt,
                                                   const bf16* __restrict__ Kr,
                                                   const bf16* __restrict__ Vt,
                                                   bf16* __restrict__ Y) {
  constexpr int PPAD = 72;                 // P row stride (elems) >= 64; 144B = 9*16B
  constexpr float LOG2E = 1.44269504f;
  constexpr float FM2 = 7.21347520f;       // 5.0*log2(e): fixed softmax shift (exp2 domain)
  // smem: Ks0[4096] Vs0[4096] Ks1[4096] Vs1[4096] P[4][32*PPAD] = 51200 B
  __shared__ __align__(16) bf16 smem[25600];
  bf16* const Ks0 = smem;
  bf16* const Vs0 = smem + 4096;
  bf16* const Ks1 = smem + 8192;
  bf16* const Vs1 = smem + 12288;
  const int idx = blockIdx.x;
  const int bh = idx & 31;
  const int q8 = (idx >> 5) & 7;
  const int qtile = (idx < 256) ? (15 - q8) : q8;  // heavy+light pair per CU: work sums const
  const int b = bh >> 4, h = bh & 15;
  const int tid = threadIdx.x, lane = tid & 63, wave = tid >> 6;
  const int quad = lane >> 4, c16 = lane & 15;
  const size_t hoff = (size_t)bh * T_SEQ * HD;
  const int q0 = qtile * 128 + wave * 32;
  const int s1 = (quad ^ (c16 & 7)) * 8;  // swizzled fragment slot, chunk 0..3
  const int s2 = s1 ^ 32;                 // chunk 4..7
  bf16* const Psw = smem + 16384 + wave * (32 * PPAD);
  // Q fragments: qf[f][dh][j] = Q[d=dh*32+quad*8+j][t=q0+f*16+c16]  (32 scalar loads, once)
  bf16x8 qf[2][2];
#pragma unroll
  for (int f = 0; f < 2; f++)
#pragma unroll
    for (int dh = 0; dh < 2; dh++)
#pragma unroll
      for (int j = 0; j < 8; j++)
        qf[f][dh][j] =
            *(const __bf16*)&Qt[hoff + (size_t)(dh * 32 + quad * 8 + j) * T_SEQ + q0 + f * 16 + c16];
  floatx4 o_acc[2][4] = {};  // o_acc[f][dt][r]: q=q0+f*16+quad*4+r, d=dt*16+c16
  float l_run[2] = {0.f, 0.f};

  // stage one 64-key tile: K rows t (64x64), V rows d (64 x 64 t-slice at kbase)
  auto stage = [&](bf16* __restrict__ Kb, bf16* __restrict__ Vb, int kbase) {
#pragma unroll
    for (int i = 0; i < 2; i++) {
      const int rw = i * 32 + (tid >> 3);                 // row within tile
      const int cs = (((tid & 7) ^ (rw & 7)) * 8);        // pre-swizzled source chunk
      gload16(&Kr[hoff + (size_t)(kbase + rw) * HD + cs], Kb + i * 2048 + wave * 512);
      gload16(&Vt[hoff + (size_t)rw * T_SEQ + kbase + cs], Vb + i * 2048 + wave * 512);
    }
  };

  auto compute = [&](const bf16* __restrict__ Kb, const bf16* __restrict__ Vb, int kbase) {
    if (kbase >= q0 + 32) return;               // fully masked for this wave
    const bool domask = (kbase + 64 > q0);
    // ---- QK^T (S^T): z[f][nt][r] holds k=kbase+nt*16+quad*4+r, q=q0+f*16+c16 ----
    floatx4 z[2][4];
#pragma unroll
    for (int nt = 0; nt < 4; nt++) {
      bf16x8 kf0 = *(const bf16x8*)&Kb[(nt * 16 + c16) * 64 + s1];
      bf16x8 kf1 = *(const bf16x8*)&Kb[(nt * 16 + c16) * 64 + s2];
#pragma unroll
      for (int f = 0; f < 2; f++) {
        floatx4 zz = {0.f, 0.f, 0.f, 0.f};
        zz = __builtin_amdgcn_mfma_f32_16x16x32_bf16(kf0, qf[f][0], zz, 0, 0, 0);
        zz = __builtin_amdgcn_mfma_f32_16x16x32_bf16(kf1, qf[f][1], zz, 0, 0, 0);
        z[f][nt] = zz;
      }
    }
    // ---- P = exp2(s*log2e - FM2), mask tail, accumulate l, store wave-private LDS ----
#pragma unroll
    for (int f = 0; f < 2; f++) {
      const int qg = q0 + f * 16 + c16;
#pragma unroll
      for (int nt = 0; nt < 4; nt++) {
        union { bf16 h4[4]; s16x4 sv; } ph;
#pragma unroll
        for (int r = 0; r < 4; r++) {
          float pp = __builtin_amdgcn_exp2f(fmaf(z[f][nt][r], LOG2E, -FM2));
          if (domask) {
            int kg = kbase + nt * 16 + quad * 4 + r;
            pp = (kg <= qg) ? pp : 0.f;
          }
          l_run[f] += pp;
          ph.h4[r] = __float2bfloat16(pp);
        }
        *(s16x4*)&Psw[(f * 16 + c16) * PPAD + nt * 16 + quad * 4] = ph.sv;
      }
    }
    // ---- PV: pf from LDS (A-operand transpose), vf from staged LDS tile ----
    bf16x8 pf[2][2];
#pragma unroll
    for (int f = 0; f < 2; f++)
#pragma unroll
      for (int ks = 0; ks < 2; ks++)
        pf[f][ks] = *(const bf16x8*)&Psw[(f * 16 + c16) * PPAD + ks * 32 + quad * 8];
#pragma unroll
    for (int dt = 0; dt < 4; dt++) {
      bf16x8 vf0 = *(const bf16x8*)&Vb[(dt * 16 + c16) * 64 + s1];
      bf16x8 vf1 = *(const bf16x8*)&Vb[(dt * 16 + c16) * 64 + s2];
#pragma unroll
      for (int f = 0; f < 2; f++) {
        o_acc[f][dt] = __builtin_amdgcn_mfma_f32_16x16x32_bf16(pf[f][0], vf0, o_acc[f][dt], 0, 0, 0);
        o_acc[f][dt] = __builtin_amdgcn_mfma_f32_16x16x32_bf16(pf[f][1], vf1, o_acc[f][dt], 0, 0, 0);
      }
    }
  };

  const int ntile = 2 * qtile + 2;  // 64-key tiles (always even)
  stage(Ks0, Vs0, 0);
  __syncthreads();  // prologue drain
  for (int kt = 0; kt < ntile; kt += 2) {
    stage(Ks1, Vs1, (kt + 1) * 64);   // issue next FIRST (kt+1 < ntile: ntile even)
    compute(Ks0, Vs0, kt * 64);
    __syncthreads();                  // drain + handoff
    if (kt + 2 < ntile) stage(Ks0, Vs0, (kt + 2) * 64);
    compute(Ks1, Vs1, (kt + 1) * 64);
    __syncthreads();
  }

  // ---- epilogue: reduce l across quads (q=c16), broadcast 1/l to rows, store O[q][d] ----
#pragma unroll
  for (int f = 0; f < 2; f++) {
    float l = l_run[f];
    l += __shfl_xor(l, 16, 64);
    l += __shfl_xor(l, 32, 64);
    float linv = 1.0f / l;
    float l_bc[4];
#pragma unroll
    for (int r = 0; r < 4; r++) l_bc[r] = __shfl(linv, quad * 4 + r, 16);
#pragma unroll
    for (int dt = 0; dt < 4; dt++)
#pragma unroll
      for (int r = 0; r < 4; r++) {
        int t = q0 + f * 16 + quad * 4 + r;
        Y[((size_t)(b * T_SEQ + t)) * CDIM + h * HD + dt * 16 + c16] =
            __float2bfloat16(o_acc[f][dt][r] * l_bc[r]);
      }
  }
}

// ---------------- launch ----------------
extern "C" void kernel_launch(void* const* d_in, const int* in_sizes, int n_in,
                              void* d_out, int out_size, void* d_ws, size_t ws_size,
                              hipStream_t stream) {
  const float* x    = (const float*)d_in[0];   // [B,T,C] fp32
  const float* Wqkv = (const float*)d_in[2];   // [C,3C] fp32
  const float* Wo   = (const float*)d_in[3];   // [C,C] fp32
  float* out = (float*)d_out;                  // [B,T,C] fp32

  bf16* ws    = (bf16*)d_ws;
  bf16* Xb    = ws;                          // [4096][1024]
  bf16* WqkvT = Xb + 4194304;                // [3072][1024]
  bf16* WoT   = WqkvT + 3072 * 1024;         // [1024][1024]
  bf16* Qt    = WoT + 1024 * 1024;           // [B,H,D,T] (pre-scaled by 0.125, transposed)
  bf16* Kr    = Qt + 4194304;                // [B,H,T,D]
  bf16* Vt    = Kr + 4194304;                // [B,H,D,T]
  bf16* Y     = Vt + 4194304;                // [B,T,C]
  float2* tab = (float2*)(Y + 4194304);      // [T][32]

  prep_kernel<<<dim3(8448), 256, 0, stream>>>(x, Wqkv, Wo, Xb, WqkvT, WoT, tab);
  gemm_bt<1><<<dim3(3072 / 128, 4096 / 128), 256, 0, stream>>>(
      Xb, WqkvT, nullptr, tab, Qt, Kr, Vt, 4096, 3072, 1024);
  attn_kernel<<<dim3(512), 256, 0, stream>>>(Qt, Kr, Vt, Y);
  gemm_bt<0><<<dim3(1024 / 128, 4096 / 128), 256, 0, stream>>>(
      Y, WoT, out, nullptr, nullptr, nullptr, nullptr, 4096, 1024, 1024);
}

// Round 6
// 182.049 us; speedup vs baseline: 1.2829x; 1.0002x over previous
//
#include <hip/hip_runtime.h>
#include <hip/hip_bf16.h>

typedef __bf16 bf16x8 __attribute__((ext_vector_type(8)));
typedef short s16x4 __attribute__((ext_vector_type(4)));
typedef float floatx4 __attribute__((ext_vector_type(4)));
typedef __hip_bfloat16 bf16;

#define T_SEQ 2048
#define NH 16
#define HD 64
#define CDIM 1024

// async global->LDS, 16B/lane. ldsbase MUST be wave-uniform; HW stores lane i at ldsbase+i*16.
__device__ __forceinline__ void gload16(const bf16* g, bf16* ldsbase) {
  __builtin_amdgcn_global_load_lds((const __attribute__((address_space(1))) void*)g,
                                   (__attribute__((address_space(3))) void*)ldsbase, 16, 0, 0);
}

// ---------------- fused prep: cast x, transpose+cast Wqkv & Wo, rope table ----------------
__global__ __launch_bounds__(256) void prep_kernel(const float* __restrict__ x,
                                                   const float* __restrict__ Wqkv,
                                                   const float* __restrict__ Wo,
                                                   bf16* __restrict__ Xb,
                                                   bf16* __restrict__ WqkvT,
                                                   bf16* __restrict__ WoT,
                                                   float2* __restrict__ tab) {
  __shared__ float tile[32][33];
  const int bid = blockIdx.x, tid = threadIdx.x;
  if (bid < 4096) {
    int i = bid * 256 + tid;
    const float4 v = ((const float4*)x)[i];
    union { bf16 h[4]; uint2 u; } pk;
    pk.h[0] = __float2bfloat16(v.x);
    pk.h[1] = __float2bfloat16(v.y);
    pk.h[2] = __float2bfloat16(v.z);
    pk.h[3] = __float2bfloat16(v.w);
    ((uint2*)Xb)[i] = pk.u;
  } else if (bid < 8192) {
    const float* in;
    bf16* out;
    int bx, by, R, Cc;
    if (bid < 7168) {
      int t = bid - 4096;
      in = Wqkv; out = WqkvT; R = 1024; Cc = 3072;
      bx = (t % 96) * 32; by = (t / 96) * 32;
    } else {
      int t = bid - 7168;
      in = Wo; out = WoT; R = 1024; Cc = 1024;
      bx = (t & 31) * 32; by = (t >> 5) * 32;
    }
    const int tx = tid & 31, ty = tid >> 5;
#pragma unroll
    for (int i = 0; i < 32; i += 8)
      tile[ty + i][tx] = in[(size_t)(by + ty + i) * Cc + bx + tx];
    __syncthreads();
#pragma unroll
    for (int i = 0; i < 32; i += 8)
      out[(size_t)(bx + ty + i) * R + by + tx] = __float2bfloat16(tile[tx][ty + i]);
  } else {
    int idx = (bid - 8192) * 256 + tid;  // 2048*32
    int t = idx >> 5, j = idx & 31;
    float w = exp2f(-13.287712379549449f * (float)(2 * j + 1) * (1.0f / 64.0f));
    float ang = (float)(t + 1) * w;
    tab[idx] = make_float2(cosf(ang), sinf(ang));
  }
}

// ---------------- 128x128x(BK=64) bf16 MFMA GEMM, B^T input, 2-PHASE DOUBLE-BUFFER ------
template <int MODE>
__global__ __launch_bounds__(256) void gemm_bt(
    const bf16* __restrict__ A, const bf16* __restrict__ BT, float* __restrict__ CoutF,
    const float2* __restrict__ tab, bf16* __restrict__ Qt, bf16* __restrict__ Kr,
    bf16* __restrict__ Vt, int M, int N, int K) {
  constexpr int LDK = 64;
  constexpr int PADC = 136;  // bf16 elems; 272B row stride = 17*16B
  __shared__ __align__(16) bf16 smem[32768];  // 64 KiB: dbuf{As,Bs}x2; epilogue reuses
  bf16* const As0 = smem;            // 8192 elems (16 KiB) each
  bf16* const Bs0 = smem + 8192;
  bf16* const As1 = smem + 16384;
  bf16* const Bs1 = smem + 24576;
  const int tid = threadIdx.x, lane = tid & 63, wave = tid >> 6;
  const int quad = lane >> 4, c16 = lane & 15;
  const int tile_m = blockIdx.y * 128, tile_n = blockIdx.x * 128;
  const int wm = (wave >> 1) * 64, wn = (wave & 1) * 64;
  const int r0 = tid >> 3;                       // staging row 0..31 (+32i)
  const int csw = ((tid & 7) ^ (r0 & 7)) * 8;    // swizzled global chunk offset (elems)
  const int s1 = (quad ^ (c16 & 7)) * 8;         // read slot, k-half 0
  const int s2 = s1 ^ 32;                        // read slot, k-half 1
  floatx4 acc[4][4] = {};

  auto stage = [&](bf16* __restrict__ Asb, bf16* __restrict__ Bsb, int k0) {
#pragma unroll
    for (int i = 0; i < 4; i++) {
      gload16(&A[(size_t)(tile_m + r0 + i * 32) * K + k0 + csw], &Asb[i * 2048 + wave * 512]);
      gload16(&BT[(size_t)(tile_n + r0 + i * 32) * K + k0 + csw], &Bsb[i * 2048 + wave * 512]);
    }
  };
  auto compute = [&](const bf16* __restrict__ Asb, const bf16* __restrict__ Bsb) {
    bf16x8 af[4], bfr[4];
#pragma unroll
    for (int i = 0; i < 4; i++) {
      af[i] = *(const bf16x8*)&Asb[(wm + i * 16 + c16) * LDK + s1];
      bfr[i] = *(const bf16x8*)&Bsb[(wn + i * 16 + c16) * LDK + s1];
    }
#pragma unroll
    for (int mi = 0; mi < 4; mi++)
#pragma unroll
      for (int ni = 0; ni < 4; ni++)
        acc[mi][ni] = __builtin_amdgcn_mfma_f32_16x16x32_bf16(af[mi], bfr[ni], acc[mi][ni], 0, 0, 0);
#pragma unroll
    for (int i = 0; i < 4; i++) {
      af[i] = *(const bf16x8*)&Asb[(wm + i * 16 + c16) * LDK + s2];
      bfr[i] = *(const bf16x8*)&Bsb[(wn + i * 16 + c16) * LDK + s2];
    }
#pragma unroll
    for (int mi = 0; mi < 4; mi++)
#pragma unroll
      for (int ni = 0; ni < 4; ni++)
        acc[mi][ni] = __builtin_amdgcn_mfma_f32_16x16x32_bf16(af[mi], bfr[ni], acc[mi][ni], 0, 0, 0);
  };

  // prologue
  stage(As0, Bs0, 0);
  __syncthreads();  // drain prologue loads (vmcnt(0)) + all waves ready
  // main: 2x unrolled so buffer selection is compile-time static
  for (int k0 = 0; k0 < K; k0 += 128) {
    if (k0 + 64 < K) stage(As1, Bs1, k0 + 64);   // issue next-tile loads FIRST
    compute(As0, Bs0);                            // MFMA hides the load latency
    __syncthreads();                              // drain + buffer handoff
    if (k0 + 128 < K) stage(As0, Bs0, k0 + 128);
    compute(As1, Bs1);
    __syncthreads();
  }
  // ---- epilogue: smem is free now (last barrier above) ----
  // C/D layout (m89): col = lane&15, row = quad*4 + reg
  if (MODE == 0) {
    // fp32 output, two 64-row passes through LDS ([64][132] fp32 = 33792 B)
    float* Ctf = (float*)smem;
#pragma unroll
    for (int p = 0; p < 2; p++) {
      if ((wave >> 1) == p) {
#pragma unroll
        for (int mi = 0; mi < 4; mi++) {
          int rl = mi * 16 + quad * 4;  // local row within this 64-row half
#pragma unroll
          for (int ni = 0; ni < 4; ni++) {
            int col = wn + ni * 16 + c16;
#pragma unroll
            for (int r = 0; r < 4; r++)
              Ctf[(rl + r) * 132 + col] = acc[mi][ni][r];
          }
        }
      }
      __syncthreads();
#pragma unroll
      for (int i = 0; i < 8; i++) {
        int e = tid + i * 256;          // 64 rows x 32 col-chunks
        int row = e >> 5, cb = (e & 31) * 4;
        floatx4 v4 = *(const floatx4*)&Ctf[row * 132 + cb];
        *(floatx4*)&CoutF[(size_t)(tile_m + p * 64 + row) * N + tile_n + cb] = v4;
      }
      __syncthreads();  // readers done before next pass overwrites
    }
  } else {
    const int seg = tile_n >> 10;  // block-uniform: 0=Q 1=K 2=V (tile never straddles segs)
    const int bq = tile_m >> 11;   // batch index (tiles never straddle batch: 128 | 2048)
    const int tg0 = tile_m & 2047; // t offset within batch
    bf16* Ct = smem;               // [128][PADC] = 34816 B, fits in 64 KiB
    if (seg != 1) {
      // Q and V go to [bh][d][t]: store Ct COLUMN-major [col][row] (row = t, contiguous)
#pragma unroll
      for (int ni = 0; ni < 4; ni++) {
        const int col = wn + ni * 16 + c16;
        const int cc = (tile_n + col) & 1023;
        const int j = (cc & 63) >> 1;
#pragma unroll
        for (int mi = 0; mi < 4; mi++) {
          const int row0 = wm + mi * 16 + quad * 4;
          union { bf16 h[4]; s16x4 sv; } ph;
#pragma unroll
          for (int r = 0; r < 4; r++) {
            float val = acc[mi][ni][r];
            float outv;
            if (seg == 0) {  // RoPE + fold 1/sqrt(D); partner lane holds col^1 (= d^1)
              float partner = __shfl_xor(val, 1, 64);
              float2 sc = tab[(tg0 + row0 + r) * 32 + j];
              outv = (((cc & 1) == 0) ? (val * sc.x - partner * sc.y)
                                      : (val * sc.x + partner * sc.y)) * 0.125f;
            } else {
              outv = val;
            }
            ph.h[r] = __float2bfloat16(outv);
          }
          *(s16x4*)&Ct[col * PADC + row0] = ph.sv;  // 8B write, 4 consecutive t
        }
      }
      __syncthreads();
      bf16* dst = (seg == 0) ? Qt : Vt;
#pragma unroll
      for (int i = 0; i < 8; i++) {
        int e = tid + i * 256;  // 128 cols x 16 t-chunks
        int col = e >> 4, tb = (e & 15) * 8;
        bf16x8 vv = *(const bf16x8*)&Ct[col * PADC + tb];
        int h = ((tile_n & 1023) + col) >> 6, d = col & 63;
        *(bf16x8*)&dst[((size_t)(bq * NH + h) * HD + d) * T_SEQ + tg0 + tb] = vv;
      }
    } else {
      // K stays [bh][t][d]: store Ct ROW-major [row][col] (col = d, contiguous)
#pragma unroll
      for (int ni = 0; ni < 4; ni++) {
        const int col = wn + ni * 16 + c16;
        const int cc = (tile_n + col) & 1023;
        const int j = (cc & 63) >> 1;
#pragma unroll
        for (int mi = 0; mi < 4; mi++) {
          const int row0 = wm + mi * 16 + quad * 4;
#pragma unroll
          for (int r = 0; r < 4; r++) {
            float val = acc[mi][ni][r];
            float partner = __shfl_xor(val, 1, 64);
            float2 sc = tab[(tg0 + row0 + r) * 32 + j];
            float outv = ((cc & 1) == 0) ? (val * sc.x - partner * sc.y)
                                         : (val * sc.x + partner * sc.y);
            Ct[(row0 + r) * PADC + col] = __float2bfloat16(outv);
          }
        }
      }
      __syncthreads();
#pragma unroll
      for (int i = 0; i < 8; i++) {
        int e = tid + i * 256;  // 128 rows x 16 d-chunks
        int row = e >> 4, db = (e & 15) * 8;
        bf16x8 vv = *(const bf16x8*)&Ct[row * PADC + db];
        int h = ((tile_n & 1023) + db) >> 6, d = db & 63;
        *(bf16x8*)&Kr[((size_t)(bq * NH + h) * T_SEQ + tg0 + row) * HD + d] = vv;
      }
    }
  }
}

// ---------------- flash attention v5: key-split partials, 1024 blocks ---------------------
// Fixed-shift softmax => partial (O, l) over disjoint key ranges are EXACTLY additive:
// O = (O0+O1)/(l0+l1). Each (bh, qtile128) splits its key tiles into two equal halves ->
// grid 512 -> 1024 (4 blocks/CU, 16 waves: the r5 occupancy fix).
// idx: bh=idx&31 (XCD-local K/V), rest=idx>>5, half=rest&1, q5=rest>>1, qtile=15-q5
// (heaviest first). Partial O (bf16) + l (f32) to workspace; combine_kernel normalizes.
// l computed via MFMA with ones-B: lands in same (quad,r) layout as o_acc (no shfl tree).
// P tile swizzled: nt ^= c16&3 on write, (2ks+(quad>>1))^(c16&3) on read (kills conflicts).
__global__ __launch_bounds__(256) void attn_kernel(const bf16* __restrict__ Qt,
                                                   const bf16* __restrict__ Kr,
                                                   const bf16* __restrict__ Vt,
                                                   bf16* __restrict__ Opart,
                                                   float* __restrict__ lpart) {
  constexpr int PPAD = 72;                 // P row stride (elems) >= 64; 144B = 9*16B
  constexpr float LOG2E = 1.44269504f;
  constexpr float FM2 = 7.21347520f;       // 5.0*log2(e): fixed softmax shift (exp2 domain)
  // smem: Ks0[4096] Vs0[4096] Ks1[4096] Vs1[4096] P[4][32*PPAD] = 51200 B
  __shared__ __align__(16) bf16 smem[25600];
  bf16* const Ks0 = smem;
  bf16* const Vs0 = smem + 4096;
  bf16* const Ks1 = smem + 8192;
  bf16* const Vs1 = smem + 12288;
  const int idx = blockIdx.x;
  const int bh = idx & 31;
  const int rest = idx >> 5;
  const int half = rest & 1, q5 = rest >> 1;
  const int qtile = 15 - q5;  // heavy blocks dispatched first
  const int tid = threadIdx.x, lane = tid & 63, wave = tid >> 6;
  const int quad = lane >> 4, c16 = lane & 15;
  const size_t hoff = (size_t)bh * T_SEQ * HD;
  const int q0 = qtile * 128 + wave * 32;
  const int s1 = (quad ^ (c16 & 7)) * 8;  // swizzled fragment slot, chunk 0..3
  const int s2 = s1 ^ 32;                 // chunk 4..7
  const int swp = c16 & 3;                // P-tile nt-slot swizzle
  bf16* const Psw = smem + 16384 + wave * (32 * PPAD);
  // Q fragments: qf[f][dh][j] = Q[d=dh*32+quad*8+j][t=q0+f*16+c16]  (32 scalar loads, once)
  bf16x8 qf[2][2];
#pragma unroll
  for (int f = 0; f < 2; f++)
#pragma unroll
    for (int dh = 0; dh < 2; dh++)
#pragma unroll
      for (int j = 0; j < 8; j++)
        qf[f][dh][j] =
            *(const __bf16*)&Qt[hoff + (size_t)(dh * 32 + quad * 8 + j) * T_SEQ + q0 + f * 16 + c16];
  bf16x8 ones;
#pragma unroll
  for (int j = 0; j < 8; j++) ones[j] = (__bf16)1.0f;
  floatx4 o_acc[2][4] = {};  // o_acc[f][dt][r]: q=q0+f*16+quad*4+r, d=dt*16+c16
  floatx4 l_acc[2] = {};     // l_acc[f][r]: same q mapping (ones-B MFMA), replicated over c16

  // stage one 64-key tile: K rows t (64x64), V rows d (64 x 64 t-slice at kbase)
  auto stage = [&](bf16* __restrict__ Kb, bf16* __restrict__ Vb, int kbase) {
#pragma unroll
    for (int i = 0; i < 2; i++) {
      const int rw = i * 32 + (tid >> 3);                 // row within tile
      const int cs = (((tid & 7) ^ (rw & 7)) * 8);        // pre-swizzled source chunk
      gload16(&Kr[hoff + (size_t)(kbase + rw) * HD + cs], Kb + i * 2048 + wave * 512);
      gload16(&Vt[hoff + (size_t)rw * T_SEQ + kbase + cs], Vb + i * 2048 + wave * 512);
    }
  };

  auto compute = [&](const bf16* __restrict__ Kb, const bf16* __restrict__ Vb, int kbase) {
    if (kbase >= q0 + 32) return;               // fully masked for this wave
    const bool domask = (kbase + 64 > q0);
    // ---- QK^T (S^T): z[f][nt][r] holds k=kbase+nt*16+quad*4+r, q=q0+f*16+c16 ----
    floatx4 z[2][4];
#pragma unroll
    for (int nt = 0; nt < 4; nt++) {
      bf16x8 kf0 = *(const bf16x8*)&Kb[(nt * 16 + c16) * 64 + s1];
      bf16x8 kf1 = *(const bf16x8*)&Kb[(nt * 16 + c16) * 64 + s2];
#pragma unroll
      for (int f = 0; f < 2; f++) {
        floatx4 zz = {0.f, 0.f, 0.f, 0.f};
        zz = __builtin_amdgcn_mfma_f32_16x16x32_bf16(kf0, qf[f][0], zz, 0, 0, 0);
        zz = __builtin_amdgcn_mfma_f32_16x16x32_bf16(kf1, qf[f][1], zz, 0, 0, 0);
        z[f][nt] = zz;
      }
    }
    // ---- P = exp2(s*log2e - FM2), mask tail, store wave-private LDS (swizzled nt) ----
#pragma unroll
    for (int f = 0; f < 2; f++) {
      const int qg = q0 + f * 16 + c16;
#pragma unroll
      for (int nt = 0; nt < 4; nt++) {
        union { bf16 h4[4]; s16x4 sv; } ph;
#pragma unroll
        for (int r = 0; r < 4; r++) {
          float pp = __builtin_amdgcn_exp2f(fmaf(z[f][nt][r], LOG2E, -FM2));
          if (domask) {
            int kg = kbase + nt * 16 + quad * 4 + r;
            pp = (kg <= qg) ? pp : 0.f;
          }
          ph.h4[r] = __float2bfloat16(pp);
        }
        *(s16x4*)&Psw[(f * 16 + c16) * PPAD + ((nt ^ swp) * 16) + quad * 4] = ph.sv;
      }
    }
    // ---- PV + l: pf from LDS (swizzled read), vf from staged tile, l via ones-B ----
    bf16x8 pf[2][2];
#pragma unroll
    for (int f = 0; f < 2; f++)
#pragma unroll
      for (int ks = 0; ks < 2; ks++)
        pf[f][ks] = *(const bf16x8*)&Psw[(f * 16 + c16) * PPAD +
                                         (((2 * ks + (quad >> 1)) ^ swp) * 16) + (quad & 1) * 8];
#pragma unroll
    for (int f = 0; f < 2; f++) {
      l_acc[f] = __builtin_amdgcn_mfma_f32_16x16x32_bf16(pf[f][0], ones, l_acc[f], 0, 0, 0);
      l_acc[f] = __builtin_amdgcn_mfma_f32_16x16x32_bf16(pf[f][1], ones, l_acc[f], 0, 0, 0);
    }
#pragma unroll
    for (int dt = 0; dt < 4; dt++) {
      bf16x8 vf0 = *(const bf16x8*)&Vb[(dt * 16 + c16) * 64 + s1];
      bf16x8 vf1 = *(const bf16x8*)&Vb[(dt * 16 + c16) * 64 + s2];
#pragma unroll
      for (int f = 0; f < 2; f++) {
        o_acc[f][dt] = __builtin_amdgcn_mfma_f32_16x16x32_bf16(pf[f][0], vf0, o_acc[f][dt], 0, 0, 0);
        o_acc[f][dt] = __builtin_amdgcn_mfma_f32_16x16x32_bf16(pf[f][1], vf1, o_acc[f][dt], 0, 0, 0);
      }
    }
  };

  // this block's key-tile range: half h covers (qtile+1) tiles starting at h*(qtile+1)
  const int ktb = half * (qtile + 1);
  const int kte = ktb + (qtile + 1);
  stage(Ks0, Vs0, ktb * 64);
  __syncthreads();  // prologue drain
  for (int kt = ktb; kt < kte; kt += 2) {
    if (kt + 1 < kte) stage(Ks1, Vs1, (kt + 1) * 64);  // issue next FIRST
    compute(Ks0, Vs0, kt * 64);
    __syncthreads();                                   // drain + handoff
    if (kt + 2 < kte) stage(Ks0, Vs0, (kt + 2) * 64);
    if (kt + 1 < kte) {
      compute(Ks1, Vs1, (kt + 1) * 64);
      __syncthreads();
    }
  }

  // ---- epilogue: wave-private repack via Psw -> coalesced full-line partial-O stores ----
#pragma unroll
  for (int f = 0; f < 2; f++)
#pragma unroll
    for (int dt = 0; dt < 4; dt++)
#pragma unroll
      for (int r = 0; r < 4; r++)
        Psw[(f * 16 + quad * 4 + r) * PPAD + dt * 16 + c16] = __float2bfloat16(o_acc[f][dt][r]);
  const size_t obase = ((size_t)idx * 128 + wave * 32) * 64;
#pragma unroll
  for (int i = 0; i < 4; i++) {
    const int row = i * 8 + (lane >> 3);
    bf16x8 v = *(const bf16x8*)&Psw[row * PPAD + (lane & 7) * 8];
    *(bf16x8*)&Opart[obase + (size_t)row * 64 + (lane & 7) * 8] = v;
  }
  if (c16 == 0) {
#pragma unroll
    for (int f = 0; f < 2; f++)
#pragma unroll
      for (int r = 0; r < 4; r++)
        lpart[idx * 128 + wave * 32 + f * 16 + quad * 4 + r] = l_acc[f][r];
  }
}

// ---------------- combine: Y = (O0+O1)/(l0+l1), bf16 out -------------------------------
__global__ __launch_bounds__(256) void combine_kernel(const bf16* __restrict__ Opart,
                                                      const float* __restrict__ lpart,
                                                      bf16* __restrict__ Y) {
  const int cb = blockIdx.x;           // 512 = (q5 0..15) x (bh 0..31)
  const int bh = cb & 31, q5 = cb >> 5;
  const int qtile = 15 - q5;
  const int b = bh >> 4, h = bh & 15;
  const int ch0 = ((q5 * 2 + 0) << 5) | bh;
  const int ch1 = ((q5 * 2 + 1) << 5) | bh;
  const int tid = threadIdx.x;
  const int q = tid >> 1, dp = (tid & 1) * 32;  // 32 d per thread
  const float inv = 1.0f / (lpart[ch0 * 128 + q] + lpart[ch1 * 128 + q]);
  const size_t o0 = ((size_t)ch0 * 128 + q) * 64 + dp;
  const size_t o1 = ((size_t)ch1 * 128 + q) * 64 + dp;
  const size_t yo = ((size_t)(b * T_SEQ + qtile * 128 + q)) * CDIM + h * HD + dp;
#pragma unroll
  for (int i = 0; i < 4; i++) {
    bf16x8 a = *(const bf16x8*)&Opart[o0 + i * 8];
    bf16x8 c = *(const bf16x8*)&Opart[o1 + i * 8];
    bf16x8 o;
#pragma unroll
    for (int j = 0; j < 8; j++) o[j] = (__bf16)(((float)a[j] + (float)c[j]) * inv);
    *(bf16x8*)&Y[yo + i * 8] = o;
  }
}

// ---------------- launch ----------------
extern "C" void kernel_launch(void* const* d_in, const int* in_sizes, int n_in,
                              void* d_out, int out_size, void* d_ws, size_t ws_size,
                              hipStream_t stream) {
  const float* x    = (const float*)d_in[0];   // [B,T,C] fp32
  const float* Wqkv = (const float*)d_in[2];   // [C,3C] fp32
  const float* Wo   = (const float*)d_in[3];   // [C,C] fp32
  float* out = (float*)d_out;                  // [B,T,C] fp32

  bf16* ws    = (bf16*)d_ws;
  bf16* Xb    = ws;                          // [4096][1024]
  bf16* WqkvT = Xb + 4194304;                // [3072][1024]
  bf16* WoT   = WqkvT + 3072 * 1024;         // [1024][1024]
  bf16* Qt    = WoT + 1024 * 1024;           // [B,H,D,T] (pre-scaled by 0.125, transposed)
  bf16* Kr    = Qt + 4194304;                // [B,H,T,D]
  bf16* Vt    = Kr + 4194304;                // [B,H,D,T]
  bf16* Y     = Vt + 4194304;                // [B,T,C]
  float2* tab = (float2*)(Y + 4194304);      // [T][32]
  bf16* Opart = (bf16*)(tab + 65536);        // [1024][128][64] bf16 partial O (16 MB)
  float* lpart = (float*)(Opart + 8388608);  // [1024][128] f32 partial l (512 KB)

  prep_kernel<<<dim3(8448), 256, 0, stream>>>(x, Wqkv, Wo, Xb, WqkvT, WoT, tab);
  gemm_bt<1><<<dim3(3072 / 128, 4096 / 128), 256, 0, stream>>>(
      Xb, WqkvT, nullptr, tab, Qt, Kr, Vt, 4096, 3072, 1024);
  attn_kernel<<<dim3(1024), 256, 0, stream>>>(Qt, Kr, Vt, Opart, lpart);
  combine_kernel<<<dim3(512), 256, 0, stream>>>(Opart, lpart, Y);
  gemm_bt<0><<<dim3(1024 / 128, 4096 / 128), 256, 0, stream>>>(
      Y, WoT, out, nullptr, nullptr, nullptr, nullptr, 4096, 1024, 1024);
}